// Round 1
// baseline (170.948 us; speedup 1.0000x reference)
//
#include <hip/hip_runtime.h>
#include <math.h>

#define EPSF 1e-8f

typedef _Float16 f16x8 __attribute__((ext_vector_type(8)));
typedef float    f32x4 __attribute__((ext_vector_type(4)));

constexpr int Bb = 8, Nn = 32768, Kk = 64, Dd = 64;
constexpr int PAD = 33;   // floats per k-row in store-staging LDS (33 -> conflict-free b128 readback)

// GEMM-ified: C[k][n] = sum_d slots[k][d] * features[n][d] via
// v_mfma_f32_16x16x32_f16 with fp32 operands split hi/lo into f16
// (3 products: hi*hi + hi*lo + lo*hi ~ fp32-accurate).
// This revision (vs 60us/dispatch baseline):
//  * 1-ahead software prefetch of the next n-tile's feature loads
//    (double-buffered raw float4 regs) so ~4KB/wave stays in flight
//    under the split+MFMA+epilogue of the current tile.
//  * Stores staged in wave-private LDS (64k x 32n, pad 33) and flushed
//    per tile-pair as 8x global_store_dwordx4 = 8 k-rows x 128B FULL
//    lines (was: 64B partial-line segments -> 86MB written vs 64MB ideal).
//  * pe staged unnormalized + per-column inv staged separately: kills
//    the p[4][4] register array to pay for the prefetch buffer.
__global__ __launch_bounds__(256, 4) void attn_kernel(
    const float* __restrict__ features,
    const float* __restrict__ slots,
    const float* __restrict__ horizons,
    float* __restrict__ out)
{
    __shared__ float s_st[Kk], s_ss2[Kk], s_rh[Kk];
    __shared__ float s_p[4][Kk * PAD];   // per-wave staging: 64 k-rows x 32 n-cols (pad->33)
    __shared__ float s_inv[4][32];       // per-wave per-column 1/sum

    const int tid  = threadIdx.x;
    const int bid  = blockIdx.x;
    const int b    = bid >> 7;        // 128 blocks per batch
    const int blk  = bid & 127;
    const int lane = tid & 63;
    const int wid  = tid >> 6;
    const int m    = lane & 15;       // MFMA row/col lane index
    const int quad = lane >> 4;

    // ---- per-block slot constants: st[k], spatial ss2[k], 1/(h+eps) ----
    if (tid < Kk) {
        const float4* sr = (const float4*)(slots + (size_t)(b * Kk + tid) * Dd);
        float4 v = sr[0];
        float st = v.x;
        float ss = v.y * v.y + v.z * v.z + v.w * v.w;   // exclude d0
        #pragma unroll
        for (int i = 1; i < 16; ++i) {
            float4 u = sr[i];
            ss += u.x * u.x + u.y * u.y + u.z * u.z + u.w * u.w;
        }
        s_st[tid]  = st;
        s_ss2[tid] = ss;
        s_rh[tid]  = 1.0f / (horizons[b * Kk + tid] + EPSF);
    }

    // ---- A fragments (slots), loaded once per wave, hi/lo split ----
    f16x8 a_hi[4][2], a_lo[4][2];
    #pragma unroll
    for (int t = 0; t < 4; ++t) {
        #pragma unroll
        for (int c = 0; c < 2; ++c) {
            const float* sp = slots + (size_t)(b * Kk + 16 * t + m) * Dd
                            + 32 * c + quad * 8;
            float4 u0 = *(const float4*)sp;
            float4 u1 = *(const float4*)(sp + 4);
            float fv[8] = {u0.x, u0.y, u0.z, u0.w, u1.x, u1.y, u1.z, u1.w};
            if (c == 0 && quad == 0) fv[0] = 0.0f;     // time dim out of dot
            #pragma unroll
            for (int j = 0; j < 8; ++j) {
                float x = fv[j];
                _Float16 h = (_Float16)x;              // RN split
                _Float16 l = (_Float16)(x - (float)h);
                a_hi[t][c][j] = h;
                a_lo[t][c][j] = l;
            }
        }
    }
    __syncthreads();

    const int base_tile = blk * 16 + wid * 4;
    float* const my_p   = s_p[wid];
    float* const my_inv = s_inv[wid];

    // ---- prologue: load tile 0 raw ----
    float4 buf[2][4];
    {
        const float* fp0 = features + (((size_t)b << 15) + (size_t)(base_tile) * 16 + m) * Dd
                         + quad * 8;
        buf[0][0] = *(const float4*)(fp0);
        buf[0][1] = *(const float4*)(fp0 + 4);
        buf[0][2] = *(const float4*)(fp0 + 32);
        buf[0][3] = *(const float4*)(fp0 + 36);
    }

    #pragma unroll
    for (int it = 0; it < 4; ++it) {
        // ---- prefetch next tile (stays in flight across this tile's compute) ----
        if (it < 3) {
            const float* fpn = features + (((size_t)b << 15) + (size_t)(base_tile + it + 1) * 16 + m) * Dd
                             + quad * 8;
            buf[(it + 1) & 1][0] = *(const float4*)(fpn);
            buf[(it + 1) & 1][1] = *(const float4*)(fpn + 4);
            buf[(it + 1) & 1][2] = *(const float4*)(fpn + 32);
            buf[(it + 1) & 1][3] = *(const float4*)(fpn + 36);
        }

        // ---- split current tile into f16 hi/lo fragments + fs2 partials ----
        f16x8 b_hi[2], b_lo[2];
        const float f00 = buf[it & 1][0].x;            // quad==0 lanes hold f[n][0]
        float fs2p = 0.f;
        #pragma unroll
        for (int c = 0; c < 2; ++c) {
            float4 u0 = buf[it & 1][2 * c];
            float4 u1 = buf[it & 1][2 * c + 1];
            float fv[8] = {u0.x, u0.y, u0.z, u0.w, u1.x, u1.y, u1.z, u1.w};
            #pragma unroll
            for (int j = 0; j < 8; ++j) {
                float x = fv[j];
                fs2p = fmaf(x, x, fs2p);
                _Float16 h = (_Float16)x;
                _Float16 l = (_Float16)(x - (float)h);
                b_hi[c][j] = h;
                b_lo[c][j] = l;
            }
        }
        const float ft = __shfl(f00, m);               // lane m (<16, quad 0)
        float fs2 = fs2p;
        fs2 += __shfl_xor(fs2, 16);
        fs2 += __shfl_xor(fs2, 32);                    // full |f|^2 over 64 d
        fs2 = fmaf(-ft, ft, fs2);                      // spatial only

        // ---- 24 MFMAs: 4 k-row-tiles x 2 d-chunks x 3 split products ----
        f32x4 acc[4];
        #pragma unroll
        for (int t = 0; t < 4; ++t) {
            f32x4 a = {0.f, 0.f, 0.f, 0.f};
            #pragma unroll
            for (int c = 0; c < 2; ++c) {
                a = __builtin_amdgcn_mfma_f32_16x16x32_f16(a_hi[t][c], b_hi[c], a, 0, 0, 0);
                a = __builtin_amdgcn_mfma_f32_16x16x32_f16(a_hi[t][c], b_lo[c], a, 0, 0, 0);
                a = __builtin_amdgcn_mfma_f32_16x16x32_f16(a_lo[t][c], b_hi[c], a, 0, 0, 0);
            }
            acc[t] = a;
        }

        // ---- epilogue: logits -> pe, stage unnormalized into LDS ----
        const int colb = (it & 1) * 16 + m;
        float sum = 0.f;
        #pragma unroll
        for (int t = 0; t < 4; ++t) {
            #pragma unroll
            for (int r = 0; r < 4; ++r) {
                const int k = 16 * t + quad * 4 + r;   // C row
                float st  = s_st[k];
                float ss2 = s_ss2[k];
                float rh  = s_rh[k];
                float cross = acc[t][r];               // spatial dot
                float dt  = ft - st;
                float dx2 = fmaf(-2.f, cross, fs2 + ss2);
                dx2 = fmaxf(dx2, 0.f);
                float interval = fmaf(dt, dt, -dx2);
                float adist = __builtin_amdgcn_sqrtf(fabsf(interval) + EPSF);
                float cone  = (fabsf(dt) - __builtin_amdgcn_sqrtf(dx2 + EPSF)) * rh;
                float e  = __expf(2.0f * cone);        // tanh via exp, NaN-free
                float th = 1.0f - 2.0f * __builtin_amdgcn_rcpf(e + 1.0f);
                float logit = fmaf(0.5f, th, -adist);  // <= +0.5: exp safe
                float pe = __expf(logit);
                my_p[k * PAD + colb] = pe;             // wave-private, no barrier
                sum += pe;
            }
        }
        sum += __shfl_xor(sum, 16);
        sum += __shfl_xor(sum, 32);                    // total over 64 k
        my_inv[colb] = __builtin_amdgcn_rcpf(sum);     // 4 quads write same bits: benign

        // ---- every odd it: flush 64 k-rows x 32 n as full 128B-line dwordx4 ----
        if (it & 1) {
            asm volatile("s_waitcnt lgkmcnt(0)" ::: "memory");  // cross-lane LDS visibility
            const int r8 = lane >> 3;
            const int c8 = lane & 7;
            const size_t npair = (size_t)(base_tile + (it - 1)) * 16;   // 128B-aligned
            float4 iv = *(const float4*)(my_inv + c8 * 4);
            float* ob = out + (((size_t)(b * Kk)) << 15) + npair + c8 * 4;
            #pragma unroll
            for (int i = 0; i < 8; ++i) {
                const int k = i * 8 + r8;
                float4 v = *(const float4*)(my_p + k * PAD + c8 * 4);
                v.x *= iv.x; v.y *= iv.y; v.z *= iv.z; v.w *= iv.w;
                *(float4*)(ob + ((size_t)k << 15)) = v;
            }
            asm volatile("s_waitcnt lgkmcnt(0)" ::: "memory");  // reads done before next pair's writes
        }
    }
}

extern "C" void kernel_launch(void* const* d_in, const int* in_sizes, int n_in,
                              void* d_out, int out_size, void* d_ws, size_t ws_size,
                              hipStream_t stream) {
    const float* features = (const float*)d_in[0];
    const float* slots    = (const float*)d_in[1];
    const float* horizons = (const float*)d_in[2];
    float* out = (float*)d_out;

    // 1024 blocks x 256 thr = 4096 waves; each wave: 4 tiles of 16 n (2 store pairs).
    hipLaunchKernelGGL(attn_kernel, dim3(1024), dim3(256), 0, stream,
                       features, slots, horizons, out);
}

// Round 2
// 127.225 us; speedup vs baseline: 1.3437x; 1.3437x over previous
//
#include <hip/hip_runtime.h>
#include <math.h>

#define EPSF 1e-8f

typedef _Float16 f16x8 __attribute__((ext_vector_type(8)));
typedef float    f32x4 __attribute__((ext_vector_type(4)));

constexpr int Bb = 8, Nn = 32768, Kk = 64, Dd = 64;

// GEMM-ified: C[k][n] = sum_d slots[k][d] * features[n][d] via
// v_mfma_f32_16x16x32_f16 with fp32 operands split hi/lo into f16
// (3 products: hi*hi + hi*lo + lo*hi ~ fp32-accurate).
//
// This revision (vs round-0 60us/dispatch; round-1 spilled at VGPR=64 and
// regressed to 85us with +110MB scratch traffic):
//  * A fragments are BLOCK-UNIFORM -> staged once per block in LDS
//    (16KB, [t*2+c][lane] f16x8 hi/lo), ds_read_b128 per t in the MFMA
//    loop. Cuts 64 persistent VGPRs/thread vs per-wave register A.
//  * 1-ahead register prefetch of the next feature tile (double-buffered
//    float4 buf) -- now affordable without spilling.
//  * pe overlays acc[t][r] (no separate p[4][4]): -16 VGPRs.
//  * Direct stores (round-0 style, 0 bank conflicts). LDS store staging
//    from round 1 is dropped (confounded by spills, added conflicts).
//  * 2048 blocks x 2 tiles/wave (was 1024x4) for scheduling granularity;
//    A-setup is cooperative (each thread splits 2 fragments) so the
//    amortization cost is negligible.
__global__ __launch_bounds__(256, 4) void attn_kernel(
    const float* __restrict__ features,
    const float* __restrict__ slots,
    const float* __restrict__ horizons,
    float* __restrict__ out)
{
    __shared__ float s_st[Kk], s_ss2[Kk], s_rh[Kk];
    __shared__ f16x8 s_ahi[8][64];   // [t*2+c][lane] -> 8KB
    __shared__ f16x8 s_alo[8][64];   // 8KB

    const int tid  = threadIdx.x;
    const int bid  = blockIdx.x;
    const int b    = bid >> 8;        // 256 blocks per batch
    const int blk  = bid & 255;
    const int lane = tid & 63;
    const int wid  = tid >> 6;
    const int m    = lane & 15;       // MFMA row/col lane index
    const int quad = lane >> 4;

    // ---- per-block slot constants: st[k], spatial ss2[k], 1/(h+eps) ----
    if (tid < Kk) {
        const float4* sr = (const float4*)(slots + (size_t)(b * Kk + tid) * Dd);
        float4 v = sr[0];
        float st = v.x;
        float ss = v.y * v.y + v.z * v.z + v.w * v.w;   // exclude d0
        #pragma unroll
        for (int i = 1; i < 16; ++i) {
            float4 u = sr[i];
            ss += u.x * u.x + u.y * u.y + u.z * u.z + u.w * u.w;
        }
        s_st[tid]  = st;
        s_ss2[tid] = ss;
        s_rh[tid]  = 1.0f / (horizons[b * Kk + tid] + EPSF);
    }

    // ---- cooperative A staging: thread (t=wid, lane) splits 2 fragments ----
    {
        const int t = wid;
        #pragma unroll
        for (int c = 0; c < 2; ++c) {
            const float* sp = slots + (size_t)(b * Kk + 16 * t + m) * Dd
                            + 32 * c + quad * 8;
            float4 u0 = *(const float4*)sp;
            float4 u1 = *(const float4*)(sp + 4);
            float fv[8] = {u0.x, u0.y, u0.z, u0.w, u1.x, u1.y, u1.z, u1.w};
            if (c == 0 && quad == 0) fv[0] = 0.0f;     // time dim out of dot
            f16x8 h8, l8;
            #pragma unroll
            for (int j = 0; j < 8; ++j) {
                float x = fv[j];
                _Float16 h = (_Float16)x;              // RN split
                _Float16 l = (_Float16)(x - (float)h);
                h8[j] = h;
                l8[j] = l;
            }
            s_ahi[t * 2 + c][lane] = h8;
            s_alo[t * 2 + c][lane] = l8;
        }
    }
    __syncthreads();

    const int base_tile = blk * 8 + wid * 2;   // 2 consecutive 16-n tiles per wave

    // ---- prologue: load tile 0 raw ----
    float4 buf[2][4];
    {
        const float* fp0 = features + (((size_t)b << 15) + (size_t)base_tile * 16 + m) * Dd
                         + quad * 8;
        buf[0][0] = *(const float4*)(fp0);
        buf[0][1] = *(const float4*)(fp0 + 4);
        buf[0][2] = *(const float4*)(fp0 + 32);
        buf[0][3] = *(const float4*)(fp0 + 36);
    }

    #pragma unroll
    for (int it = 0; it < 2; ++it) {
        // ---- prefetch next tile (in flight across this tile's compute) ----
        if (it == 0) {
            const float* fpn = features + (((size_t)b << 15) + (size_t)(base_tile + 1) * 16 + m) * Dd
                             + quad * 8;
            buf[1][0] = *(const float4*)(fpn);
            buf[1][1] = *(const float4*)(fpn + 4);
            buf[1][2] = *(const float4*)(fpn + 32);
            buf[1][3] = *(const float4*)(fpn + 36);
        }
        const int n0 = (base_tile + it) * 16;

        // ---- split current tile into f16 hi/lo fragments + fs2 partials ----
        f16x8 b_hi[2], b_lo[2];
        const float f00 = buf[it][0].x;        // quad==0 lanes hold f[n][0]
        float fs2p = 0.f;
        #pragma unroll
        for (int c = 0; c < 2; ++c) {
            float4 u0 = buf[it][2 * c];
            float4 u1 = buf[it][2 * c + 1];
            float fv[8] = {u0.x, u0.y, u0.z, u0.w, u1.x, u1.y, u1.z, u1.w};
            #pragma unroll
            for (int j = 0; j < 8; ++j) {
                float x = fv[j];
                fs2p = fmaf(x, x, fs2p);
                _Float16 h = (_Float16)x;
                _Float16 l = (_Float16)(x - (float)h);
                b_hi[c][j] = h;
                b_lo[c][j] = l;
            }
        }
        const float ft = __shfl(f00, m);       // lane m (<16, quad 0)
        float fs2 = fs2p;
        fs2 += __shfl_xor(fs2, 16);
        fs2 += __shfl_xor(fs2, 32);            // full |f|^2 over 64 d
        fs2 = fmaf(-ft, ft, fs2);              // spatial only

        // ---- 24 MFMAs: A frags streamed from LDS per t ----
        f32x4 acc[4];
        #pragma unroll
        for (int t = 0; t < 4; ++t) {
            f16x8 ah0 = s_ahi[t * 2 + 0][lane];
            f16x8 ah1 = s_ahi[t * 2 + 1][lane];
            f16x8 al0 = s_alo[t * 2 + 0][lane];
            f16x8 al1 = s_alo[t * 2 + 1][lane];
            f32x4 a = {0.f, 0.f, 0.f, 0.f};
            a = __builtin_amdgcn_mfma_f32_16x16x32_f16(ah0, b_hi[0], a, 0, 0, 0);
            a = __builtin_amdgcn_mfma_f32_16x16x32_f16(ah0, b_lo[0], a, 0, 0, 0);
            a = __builtin_amdgcn_mfma_f32_16x16x32_f16(al0, b_hi[0], a, 0, 0, 0);
            a = __builtin_amdgcn_mfma_f32_16x16x32_f16(ah1, b_hi[1], a, 0, 0, 0);
            a = __builtin_amdgcn_mfma_f32_16x16x32_f16(ah1, b_lo[1], a, 0, 0, 0);
            a = __builtin_amdgcn_mfma_f32_16x16x32_f16(al1, b_hi[1], a, 0, 0, 0);
            acc[t] = a;
        }

        // ---- epilogue: logits -> pe (overlaid into acc), running sum ----
        float sum = 0.f;
        #pragma unroll
        for (int t = 0; t < 4; ++t) {
            #pragma unroll
            for (int r = 0; r < 4; ++r) {
                const int k = 16 * t + quad * 4 + r;   // C row
                float st  = s_st[k];
                float ss2 = s_ss2[k];
                float rh  = s_rh[k];
                float cross = acc[t][r];               // spatial dot
                float dt  = ft - st;
                float dx2 = fmaf(-2.f, cross, fs2 + ss2);
                dx2 = fmaxf(dx2, 0.f);
                float interval = fmaf(dt, dt, -dx2);
                float adist = __builtin_amdgcn_sqrtf(fabsf(interval) + EPSF);
                float cone  = (fabsf(dt) - __builtin_amdgcn_sqrtf(dx2 + EPSF)) * rh;
                float e  = __expf(2.0f * cone);        // tanh via exp, NaN-free
                float th = 1.0f - 2.0f * __builtin_amdgcn_rcpf(e + 1.0f);
                float logit = fmaf(0.5f, th, -adist);  // <= +0.5: exp safe
                float pe = __expf(logit);
                acc[t][r] = pe;                        // overlay: acc reused as p
                sum += pe;
            }
        }
        sum += __shfl_xor(sum, 16);
        sum += __shfl_xor(sum, 32);                    // total over 64 k
        const float inv = __builtin_amdgcn_rcpf(sum);

        // ---- stores: per (t,r) instr writes 4 k-rows x 64B contiguous ----
        float* ob = out + (((size_t)(b * Kk)) << 15) + n0 + m;
        #pragma unroll
        for (int t = 0; t < 4; ++t) {
            #pragma unroll
            for (int r = 0; r < 4; ++r) {
                const int k = 16 * t + quad * 4 + r;
                ob[(size_t)k << 15] = acc[t][r] * inv;
            }
        }
    }
}

extern "C" void kernel_launch(void* const* d_in, const int* in_sizes, int n_in,
                              void* d_out, int out_size, void* d_ws, size_t ws_size,
                              hipStream_t stream) {
    const float* features = (const float*)d_in[0];
    const float* slots    = (const float*)d_in[1];
    const float* horizons = (const float*)d_in[2];
    float* out = (float*)d_out;

    // 2048 blocks x 256 thr = 8192 waves; each wave: 2 tiles of 16 n.
    hipLaunchKernelGGL(attn_kernel, dim3(2048), dim3(256), 0, stream,
                       features, slots, horizons, out);
}

// Round 3
// 125.286 us; speedup vs baseline: 1.3645x; 1.0155x over previous
//
#include <hip/hip_runtime.h>
#include <math.h>

#define EPSF 1e-8f

typedef _Float16 f16x8 __attribute__((ext_vector_type(8)));
typedef float    f32x4 __attribute__((ext_vector_type(4)));

constexpr int Bb = 8, Nn = 32768, Kk = 64, Dd = 64;

// GEMM-ified: C[k][n] = sum_d slots[k][d] * features[n][d] via
// v_mfma_f32_16x16x32_f16 with fp32 operands split hi/lo into f16
// (3 products: hi*hi + hi*lo + lo*hi ~ fp32-accurate).
//
// Round-3 revision (round-2 = 43.6us/dispatch, VALUBusy 35%, MfmaUtil 5.5%,
// occupancy ~2.2 waves/SIMD, HBM clean -> on-chip latency/ILP-bound):
//  * FUSE the wave's two 16-col tiles into one pass:
//      - both tile loads issued up front (8 dwordx4 in flight)
//      - per A-frag ds_read, TWO independent 6-MFMA chains (2x matrix ILP,
//        1/2 the A LDS traffic)
//      - epilogue constants packed (st,ss2,rh) into ONE float4 LDS read
//        shared by both tiles: 96 ds_read_b32 -> 16 ds_read_b128 per wave
//      - 2x independent transcendental chains in the epilogue
//      - stores pair n0/n0+16 -> full 128B lines
//  * acc/A-frags live in AGPRs (unified file): round-2's VGPR_Count=64 was
//    the VGPR half only. Fusion adds ~48 regs -> launch_bounds(256,3)
//    (cap 512/3=168) so the allocator cannot spill (round-1 lesson: spill
//    = +110MB scratch traffic = +40us).
__global__ __launch_bounds__(256, 3) void attn_kernel(
    const float* __restrict__ features,
    const float* __restrict__ slots,
    const float* __restrict__ horizons,
    float* __restrict__ out)
{
    __shared__ float4 s_kp[Kk];      // (st, ss2_spatial, 1/(h+eps), pad)
    __shared__ f16x8 s_ahi[8][64];   // [t*2+c][lane] 8KB
    __shared__ f16x8 s_alo[8][64];   // 8KB

    const int tid  = threadIdx.x;
    const int bid  = blockIdx.x;
    const int b    = bid >> 8;        // 256 blocks per batch
    const int blk  = bid & 255;
    const int lane = tid & 63;
    const int wid  = tid >> 6;
    const int m    = lane & 15;       // MFMA row/col lane index
    const int quad = lane >> 4;

    // ---- per-block slot constants, packed ----
    if (tid < Kk) {
        const float4* sr = (const float4*)(slots + (size_t)(b * Kk + tid) * Dd);
        float4 v = sr[0];
        float st = v.x;
        float ss = v.y * v.y + v.z * v.z + v.w * v.w;   // exclude d0
        #pragma unroll
        for (int i = 1; i < 16; ++i) {
            float4 u = sr[i];
            ss += u.x * u.x + u.y * u.y + u.z * u.z + u.w * u.w;
        }
        s_kp[tid] = make_float4(st, ss, 1.0f / (horizons[b * Kk + tid] + EPSF), 0.f);
    }

    // ---- cooperative A staging: thread (t=wid, lane) splits 2 fragments ----
    {
        const int t = wid;
        #pragma unroll
        for (int c = 0; c < 2; ++c) {
            const float* sp = slots + (size_t)(b * Kk + 16 * t + m) * Dd
                            + 32 * c + quad * 8;
            float4 u0 = *(const float4*)sp;
            float4 u1 = *(const float4*)(sp + 4);
            float fv[8] = {u0.x, u0.y, u0.z, u0.w, u1.x, u1.y, u1.z, u1.w};
            if (c == 0 && quad == 0) fv[0] = 0.0f;     // time dim out of dot
            f16x8 h8, l8;
            #pragma unroll
            for (int j = 0; j < 8; ++j) {
                float x = fv[j];
                _Float16 h = (_Float16)x;              // RN split
                _Float16 l = (_Float16)(x - (float)h);
                h8[j] = h;
                l8[j] = l;
            }
            s_ahi[t * 2 + c][lane] = h8;
            s_alo[t * 2 + c][lane] = l8;
        }
    }
    __syncthreads();

    const int base_tile = blk * 8 + wid * 2;   // 2 consecutive 16-n tiles, fused
    const int n0 = base_tile * 16;

    // ---- both tiles' loads issued back-to-back, all in flight ----
    float4 buf[2][4];
    #pragma unroll
    for (int it = 0; it < 2; ++it) {
        const float* fp = features + (((size_t)b << 15) + n0 + it * 16 + m) * Dd
                        + quad * 8;
        buf[it][0] = *(const float4*)(fp);
        buf[it][1] = *(const float4*)(fp + 4);
        buf[it][2] = *(const float4*)(fp + 32);
        buf[it][3] = *(const float4*)(fp + 36);
    }

    // ---- split both tiles into f16 hi/lo fragments + fs2 ----
    f16x8 bh[2][2], bl[2][2];
    float ft0, ft1, fs20, fs21;
    #pragma unroll
    for (int it = 0; it < 2; ++it) {
        const float f00 = buf[it][0].x;        // quad==0 lanes hold f[n][0]
        float s = 0.f;
        #pragma unroll
        for (int c = 0; c < 2; ++c) {
            float4 u0 = buf[it][2 * c];
            float4 u1 = buf[it][2 * c + 1];
            float fv[8] = {u0.x, u0.y, u0.z, u0.w, u1.x, u1.y, u1.z, u1.w};
            #pragma unroll
            for (int j = 0; j < 8; ++j) {
                float x = fv[j];
                s = fmaf(x, x, s);
                _Float16 h = (_Float16)x;
                _Float16 l = (_Float16)(x - (float)h);
                bh[it][c][j] = h;
                bl[it][c][j] = l;
            }
        }
        float f = __shfl(f00, m);              // lane m (<16, quad 0)
        s += __shfl_xor(s, 16);
        s += __shfl_xor(s, 32);                // full |f|^2 over 64 d
        s = fmaf(-f, f, s);                    // spatial only
        if (it == 0) { ft0 = f; fs20 = s; } else { ft1 = f; fs21 = s; }
    }

    // ---- 48 MFMAs: per A-read, 2 independent 6-chains (2x matrix ILP) ----
    f32x4 acc[2][4];
    #pragma unroll
    for (int t = 0; t < 4; ++t) {
        f16x8 ah0 = s_ahi[t * 2 + 0][lane];
        f16x8 ah1 = s_ahi[t * 2 + 1][lane];
        f16x8 al0 = s_alo[t * 2 + 0][lane];
        f16x8 al1 = s_alo[t * 2 + 1][lane];
        #pragma unroll
        for (int it = 0; it < 2; ++it) {
            f32x4 a = {0.f, 0.f, 0.f, 0.f};
            a = __builtin_amdgcn_mfma_f32_16x16x32_f16(ah0, bh[it][0], a, 0, 0, 0);
            a = __builtin_amdgcn_mfma_f32_16x16x32_f16(ah0, bl[it][0], a, 0, 0, 0);
            a = __builtin_amdgcn_mfma_f32_16x16x32_f16(al0, bh[it][0], a, 0, 0, 0);
            a = __builtin_amdgcn_mfma_f32_16x16x32_f16(ah1, bh[it][1], a, 0, 0, 0);
            a = __builtin_amdgcn_mfma_f32_16x16x32_f16(ah1, bl[it][1], a, 0, 0, 0);
            a = __builtin_amdgcn_mfma_f32_16x16x32_f16(al1, bh[it][1], a, 0, 0, 0);
            acc[it][t] = a;
        }
    }

    // ---- epilogue: one packed kparam read serves both tiles ----
    float sum0 = 0.f, sum1 = 0.f;
    #pragma unroll
    for (int t = 0; t < 4; ++t) {
        #pragma unroll
        for (int r = 0; r < 4; ++r) {
            const int k = 16 * t + quad * 4 + r;   // C row
            float4 kp = s_kp[k];                   // st, ss2, rh
            #pragma unroll
            for (int it = 0; it < 2; ++it) {
                float cross = acc[it][t][r];
                float ftv = (it == 0) ? ft0 : ft1;
                float fsv = (it == 0) ? fs20 : fs21;
                float dt  = ftv - kp.x;
                float dx2 = fmaf(-2.f, cross, fsv + kp.y);
                dx2 = fmaxf(dx2, 0.f);
                float interval = fmaf(dt, dt, -dx2);
                float adist = __builtin_amdgcn_sqrtf(fabsf(interval) + EPSF);
                float cone  = (fabsf(dt) - __builtin_amdgcn_sqrtf(dx2 + EPSF)) * kp.z;
                float e  = __expf(2.0f * cone);    // tanh via exp, NaN-free
                float th = 1.0f - 2.0f * __builtin_amdgcn_rcpf(e + 1.0f);
                float logit = fmaf(0.5f, th, -adist);  // <= +0.5: exp safe
                float pe = __expf(logit);
                acc[it][t][r] = pe;                // overlay: acc reused as p
                if (it == 0) sum0 += pe; else sum1 += pe;
            }
        }
    }
    sum0 += __shfl_xor(sum0, 16);
    sum0 += __shfl_xor(sum0, 32);
    sum1 += __shfl_xor(sum1, 16);
    sum1 += __shfl_xor(sum1, 32);
    const float inv0 = __builtin_amdgcn_rcpf(sum0);
    const float inv1 = __builtin_amdgcn_rcpf(sum1);

    // ---- stores: n0/n0+16 pair -> full 128B line per quad k-row ----
    float* ob = out + (((size_t)(b * Kk)) << 15) + n0 + m;
    #pragma unroll
    for (int t = 0; t < 4; ++t) {
        #pragma unroll
        for (int r = 0; r < 4; ++r) {
            const int k = 16 * t + quad * 4 + r;
            ob[(size_t)k << 15]        = acc[0][t][r] * inv0;
            ob[((size_t)k << 15) + 16] = acc[1][t][r] * inv1;
        }
    }
}

extern "C" void kernel_launch(void* const* d_in, const int* in_sizes, int n_in,
                              void* d_out, int out_size, void* d_ws, size_t ws_size,
                              hipStream_t stream) {
    const float* features = (const float*)d_in[0];
    const float* slots    = (const float*)d_in[1];
    const float* horizons = (const float*)d_in[2];
    float* out = (float*)d_out;

    // 2048 blocks x 256 thr = 8192 waves; each wave: 2 fused tiles of 16 n.
    hipLaunchKernelGGL(attn_kernel, dim3(2048), dim3(256), 0, stream,
                       features, slots, horizons, out);
}